// Round 1
// baseline (836.830 us; speedup 1.0000x reference)
//
#include <hip/hip_runtime.h>
#include <math.h>

#define NN 100000
#define NE 3200000
#define FIN 512
#define HID 16
#define NC 40

// ---------------------------------------------------------------- degree ----
__global__ __launch_bounds__(256) void k_deg_init(float* __restrict__ deg) {
    int i = blockIdx.x * 256 + threadIdx.x;
    if (i < NN) deg[i] = 1.0f;   // self-loop contributes 1 to every node
}

__global__ __launch_bounds__(256) void k_deg_count(const int* __restrict__ dst,
                                                   float* __restrict__ deg) {
    int e = blockIdx.x * 256 + threadIdx.x;
    if (e < NE) atomicAdd(&deg[dst[e]], 1.0f);
}

__global__ __launch_bounds__(256) void k_dinv(float* __restrict__ deg) {
    int i = blockIdx.x * 256 + threadIdx.x;
    if (i < NN) deg[i] = rsqrtf(deg[i]);   // deg >= 1 always
}

// ------------------------------------------- layer1 + Wg transform ----------
// h1 = relu(x @ W1^T + b1); h2 = h1 @ Wg^T; agg_init = h2 * dinv^2 (self loop)
__global__ __launch_bounds__(256) void k_h2(const float* __restrict__ x,
                                            const float* __restrict__ W1,
                                            const float* __restrict__ b1,
                                            const float* __restrict__ Wg,
                                            const float* __restrict__ dinv,
                                            float* __restrict__ h2,
                                            float* __restrict__ agg) {
    __shared__ float xs[256 * 33];   // 256 rows x 32 cols, +1 pad
    const int t  = threadIdx.x;
    const int n0 = blockIdx.x * 256;
    const int n  = n0 + t;

    float acc[HID];
#pragma unroll
    for (int j = 0; j < HID; ++j) acc[j] = 0.0f;

    const int lrow = t >> 3;          // 0..31
    const int lcol = (t & 7) * 4;     // 0,4,...,28

    for (int kc = 0; kc < FIN; kc += 32) {
        // cooperative, coalesced load of a 256x32 fp32 tile
#pragma unroll
        for (int pass = 0; pass < 8; ++pass) {
            int row = pass * 32 + lrow;
            int g = n0 + row;
            if (g > NN - 1) g = NN - 1;                 // clamp (safe re-read)
            const float4 v = *(const float4*)(x + (size_t)g * FIN + kc + lcol);
            xs[row * 33 + lcol + 0] = v.x;
            xs[row * 33 + lcol + 1] = v.y;
            xs[row * 33 + lcol + 2] = v.z;
            xs[row * 33 + lcol + 3] = v.w;
        }
        __syncthreads();
#pragma unroll
        for (int k = 0; k < 32; ++k) {
            const float xv = xs[t * 33 + k];
            const float* wp = W1 + kc + k;              // uniform across wave
#pragma unroll
            for (int j = 0; j < HID; ++j)
                acc[j] = fmaf(xv, wp[j * FIN], acc[j]);
        }
        __syncthreads();
    }

    // epilogue: bias + relu, then Wg
    float h1[HID];
#pragma unroll
    for (int j = 0; j < HID; ++j) h1[j] = fmaxf(acc[j] + b1[j], 0.0f);

    float hv[HID];
#pragma unroll
    for (int f = 0; f < HID; ++f) {
        float s = 0.0f;
#pragma unroll
        for (int j = 0; j < HID; ++j) s = fmaf(h1[j], Wg[f * HID + j], s);
        hv[f] = s;
    }

    if (n < NN) {
        const float di = dinv[n];
        const float d2 = di * di;
        float4* hp = (float4*)(h2  + (size_t)n * HID);
        float4* ap = (float4*)(agg + (size_t)n * HID);
#pragma unroll
        for (int q = 0; q < 4; ++q) {
            float4 v = make_float4(hv[4*q+0], hv[4*q+1], hv[4*q+2], hv[4*q+3]);
            hp[q] = v;
            ap[q] = make_float4(v.x * d2, v.y * d2, v.z * d2, v.w * d2);
        }
    }
}

// ------------------------------------------------------ edge scatter --------
// 16 lanes per edge: agg[dst][f] += h2[src][f] * dinv[src]*dinv[dst]
__global__ __launch_bounds__(256) void k_scatter(const int* __restrict__ esrc,
                                                 const int* __restrict__ edst,
                                                 const float* __restrict__ dinv,
                                                 const float* __restrict__ h2,
                                                 float* __restrict__ agg) {
    int t = blockIdx.x * 256 + threadIdx.x;    // NE*16 = 51.2M < 2^31
    if (t >= NE * HID) return;
    int e = t >> 4;
    int f = t & 15;
    int s = esrc[e];
    int d = edst[e];
    float nrm = dinv[s] * dinv[d];
    atomicAdd(&agg[(size_t)d * HID + f], h2[(size_t)s * HID + f] * nrm);
}

// --------------------------------------- classifier + log_softmax -----------
__global__ __launch_bounds__(256) void k_final(const float* __restrict__ agg,
                                               const float* __restrict__ bg,
                                               const float* __restrict__ W2,
                                               const float* __restrict__ b2,
                                               float* __restrict__ out) {
    int n = blockIdx.x * 256 + threadIdx.x;
    if (n >= NN) return;

    float v[HID];
    const float4* ap = (const float4*)(agg + (size_t)n * HID);
#pragma unroll
    for (int q = 0; q < 4; ++q) {
        float4 a = ap[q];
        v[4*q+0] = a.x; v[4*q+1] = a.y; v[4*q+2] = a.z; v[4*q+3] = a.w;
    }
#pragma unroll
    for (int j = 0; j < HID; ++j) v[j] = fmaxf(v[j] + bg[j], 0.0f);

    float lg[NC];
    float m = -1e30f;
#pragma unroll
    for (int c = 0; c < NC; ++c) {
        float s = b2[c];
#pragma unroll
        for (int j = 0; j < HID; ++j) s = fmaf(v[j], W2[c * HID + j], s);
        lg[c] = s;
        m = fmaxf(m, s);
    }
    float se = 0.0f;
#pragma unroll
    for (int c = 0; c < NC; ++c) se += expf(lg[c] - m);
    const float lse = m + logf(se);

    float4* op = (float4*)(out + (size_t)n * NC);
#pragma unroll
    for (int q = 0; q < NC / 4; ++q)
        op[q] = make_float4(lg[4*q+0] - lse, lg[4*q+1] - lse,
                            lg[4*q+2] - lse, lg[4*q+3] - lse);
}

// ---------------------------------------------------------------- launch ----
extern "C" void kernel_launch(void* const* d_in, const int* in_sizes, int n_in,
                              void* d_out, int out_size, void* d_ws, size_t ws_size,
                              hipStream_t stream) {
    const float* x   = (const float*)d_in[0];
    const int*   ei  = (const int*)d_in[1];     // [2, NE] int32
    const float* W1  = (const float*)d_in[2];
    const float* b1  = (const float*)d_in[3];
    const float* Wg  = (const float*)d_in[4];
    const float* bg  = (const float*)d_in[5];
    const float* W2  = (const float*)d_in[6];
    const float* b2  = (const float*)d_in[7];
    float*       out = (float*)d_out;

    const int* esrc = ei;
    const int* edst = ei + NE;

    // workspace layout (fp32): deg/dinv [NN] | h2 [NN*16] | agg [NN*16]
    float* deg = (float*)d_ws;
    float* h2  = deg + NN;
    float* agg = h2 + (size_t)NN * HID;

    const int nodeBlocks = (NN + 255) / 256;        // 391
    const int edgeBlocks = (NE + 255) / 256;        // 12500
    const int scatBlocks = (NE * HID + 255) / 256;  // 200000

    k_deg_init<<<nodeBlocks, 256, 0, stream>>>(deg);
    k_deg_count<<<edgeBlocks, 256, 0, stream>>>(edst, deg);
    k_dinv<<<nodeBlocks, 256, 0, stream>>>(deg);
    k_h2<<<nodeBlocks, 256, 0, stream>>>(x, W1, b1, Wg, deg, h2, agg);
    k_scatter<<<scatBlocks, 256, 0, stream>>>(esrc, edst, deg, h2, agg);
    k_final<<<nodeBlocks, 256, 0, stream>>>(agg, bg, W2, b2, out);
}